// Round 4
// baseline (686.726 us; speedup 1.0000x reference)
//
#include <hip/hip_runtime.h>
#include <math.h>

#define MM 64
#define NA 24
#define NP 276
#define NT 6000
#define QC 0.22360679774997896f
#define EXPC 0.01666666666666667f  // 5/(3*sig^2), sig=10

// ws layout (float offsets)
#define OFF_XS   0                 // 64*276
#define OFF_UU   17664             // 64
#define OFF_VV   17728             // 6000
#define OFF_C1   23728             // 6000
#define OFF_F1P  29728             // 64*276 (zeroed)
#define OFF_F2   47392             // 64*276 (zeroed)
#define OFF_ES   65056             // 64     (zeroed)
#define OFF_SW   65120             // 64     (zeroed)
#define OFF_W    65184             // 64*6000
#define OFF_E1   449184            // 64*6000
#define ZTOT     35456             // floats to zero at OFF_F1P

__device__ __forceinline__ float f4c(const float4& v, int i) {
  return i == 0 ? v.x : i == 1 ? v.y : i == 2 ? v.z : v.w;
}

// ---------- kernel 1: prep (xs, uu) + stats (vv, c1) + zero accumulators ----------
__global__ __launch_bounds__(256) void k_pre(const float* __restrict__ Rs,
                                             const float* __restrict__ xt,
                                             const float* __restrict__ Ja,
                                             float* __restrict__ ws) {
  const int tid = threadIdx.x;
  for (int z = blockIdx.x * 256 + tid; z < ZTOT; z += gridDim.x * 256)
    ws[OFF_F1P + z] = 0.f;

  if (blockIdx.x < MM) {
    const int m = blockIdx.x;
    __shared__ float sR[NA * 3];
    __shared__ float sAcc[4];
    if (tid < NA * 3) sR[tid] = Rs[m * NA * 3 + tid];
    __syncthreads();
    float acc = 0.f;
    for (int p = tid; p < NP; p += 256) {
      int i = (int)((1.0f + sqrtf(1.0f + 8.0f * (float)p)) * 0.5f);
      while (i * (i - 1) / 2 > p) i--;
      while ((i + 1) * i / 2 <= p) i++;
      int j = p - i * (i - 1) / 2;
      float dx = sR[i * 3 + 0] - sR[j * 3 + 0];
      float dy = sR[i * 3 + 1] - sR[j * 3 + 1];
      float dz = sR[i * 3 + 2] - sR[j * 3 + 2];
      float u = 1.0f / sqrtf(dx * dx + dy * dy + dz * dz);
      ws[OFF_XS + m * NP + p] = u;
      acc += u * u;
    }
    for (int off = 32; off; off >>= 1) acc += __shfl_down(acc, off);
    if ((tid & 63) == 0) sAcc[tid >> 6] = acc;
    __syncthreads();
    if (tid == 0) ws[OFF_UU + m] = sAcc[0] + sAcc[1] + sAcc[2] + sAcc[3];
  } else {
    const int t = (blockIdx.x - MM) * 4 + (tid >> 6);
    const int lane = tid & 63;
    if (t < NT) {
      const float* vrow = xt + (size_t)t * NP;
      const float* jrow = Ja + (size_t)t * NP;
      float a = 0.f, b = 0.f;
      for (int p = lane; p < NP; p += 64) {
        float v = vrow[p], j = jrow[p];
        a += v * v;
        b += v * j;
      }
      for (int off = 32; off; off >>= 1) {
        a += __shfl_down(a, off);
        b += __shfl_down(b, off);
      }
      if (lane == 0) { ws[OFF_VV + t] = a; ws[OFF_C1 + t] = b; }
    }
  }
}

// ---------- kernel 2: fused GEMM1 + elementwise ----------
// out tile 64m x 16t; B (xt,Ja interleaved, K=276 zero-padded to 288) staged in
// LDS once; A (xs, L2-hot 70KB) streamed with an explicit branchless 3-stage
// software pipeline. One barrier total. Thread = 4m x 1t x 2mat.
#define G1_TD 16
#define G1_STR 292  // float2 per t-row; covers compute reads up to idx 287
__global__ __launch_bounds__(256) void k_g1(const float* __restrict__ xt,
                                            const float* __restrict__ Ja,
                                            float* __restrict__ ws) {
  __shared__ __align__(16) float2 Bs[G1_TD][G1_STR];
  const int tid = threadIdx.x;
  const int t0 = blockIdx.x * G1_TD;
  const int c = tid & 15;   // t-column
  const int r = tid >> 4;   // m-group: m = 4r..4r+3

  // stage B: (v,j) interleaved, zero-padded for k in [276,288)
  {
    const int row = tid >> 4;
    const int kg = tid & 15;
    const float* xrow = xt + (size_t)(t0 + row) * NP;
    const float* jrow = Ja + (size_t)(t0 + row) * NP;
#pragma unroll
    for (int it = 0; it < 9; it++) {
      const int k = kg * 2 + it * 32;  // even, covers 0..286
      float4 val = make_float4(0.f, 0.f, 0.f, 0.f);
      if (k < NP) {
        float2 v = *(const float2*)(xrow + k);
        float2 j = *(const float2*)(jrow + k);
        val = make_float4(v.x, j.x, v.y, j.y);
      }
      *(float4*)(&Bs[row][k]) = val;
    }
  }
  const float* xs = ws + OFF_XS;
  const float4 uu4 = *(const float4*)(ws + OFF_UU + r * 4);
  const float vvt = ws[OFF_VV + t0 + c];
  const float c1t = ws[OFF_C1 + t0 + c];

  const float* ar[4];
#pragma unroll
  for (int i = 0; i < 4; i++) ar[i] = xs + (r * 4 + i) * NP;

  // prologue: A prefetch for pipeline stages 0..2 (global, pre-barrier OK)
  float4 A[3][4];
#pragma unroll
  for (int s = 0; s < 3; s++)
#pragma unroll
    for (int i = 0; i < 4; i++) A[s][i] = *(const float4*)(ar[i] + 4 * s);

  __syncthreads();

  float4 Bv[3][2];
#pragma unroll
  for (int s = 0; s < 3; s++) {
    Bv[s][0] = *(const float4*)(&Bs[c][4 * s]);
    Bv[s][1] = *(const float4*)(&Bs[c][4 * s + 2]);
  }

  float accv[4] = {0.f, 0.f, 0.f, 0.f};
  float accj[4] = {0.f, 0.f, 0.f, 0.f};

  // 69 k4-iterations, 3-stage rotation. Tail prefetches (iters 69..71) read
  // A past the row end (lands in ws's uu/vv region - valid memory) and B pad
  // (zeros) - products with B=0 contribute nothing.
  for (int kk = 0; kk < 69; kk += 3) {
#pragma unroll
    for (int s = 0; s < 3; s++) {
      const float4 b0 = Bv[s][0], b1 = Bv[s][1];
#pragma unroll
      for (int i = 0; i < 4; i++) {
        const float4 a = A[s][i];
        accv[i] = fmaf(a.x, b0.x, accv[i]); accj[i] = fmaf(a.x, b0.y, accj[i]);
        accv[i] = fmaf(a.y, b0.z, accv[i]); accj[i] = fmaf(a.y, b0.w, accj[i]);
        accv[i] = fmaf(a.z, b1.x, accv[i]); accj[i] = fmaf(a.z, b1.y, accj[i]);
        accv[i] = fmaf(a.w, b1.z, accv[i]); accj[i] = fmaf(a.w, b1.w, accj[i]);
      }
      const int kn = kk + s + 3;
#pragma unroll
      for (int i = 0; i < 4; i++) A[s][i] = *(const float4*)(ar[i] + 4 * kn);
      Bv[s][0] = *(const float4*)(&Bs[c][4 * kn]);
      Bv[s][1] = *(const float4*)(&Bs[c][4 * kn + 2]);
    }
  }

  // fused elementwise epilogue
  float es_p[4], sw_p[4];
#pragma unroll
  for (int i = 0; i < 4; i++) {
    const float g1v = accv[i], g2v = accj[i];
    float d2 = fmaxf(f4c(uu4, i) - 2.f * g1v + vvt, 0.f);
    float xd = QC * sqrtf(d2);
    float dv = QC * (g2v - c1t);
    float ex = EXPC * __expf(-xd);
    float e1v = ex * (1.f + xd);
    float w_ = ex * dv;
    ws[OFF_W + (r * 4 + i) * NT + t0 + c] = w_;
    ws[OFF_E1 + (r * 4 + i) * NT + t0 + c] = e1v;
    es_p[i] = e1v * dv;
    sw_p[i] = w_;
  }
#pragma unroll
  for (int off = 8; off; off >>= 1) {
#pragma unroll
    for (int i = 0; i < 4; i++) {
      es_p[i] += __shfl_down(es_p[i], off, 16);
      sw_p[i] += __shfl_down(sw_p[i], off, 16);
    }
  }
  if (c == 0) {
#pragma unroll
    for (int i = 0; i < 4; i++) {
      atomicAdd(ws + OFF_ES + r * 4 + i, es_p[i]);
      atomicAdd(ws + OFF_SW + r * 4 + i, sw_p[i]);
    }
  }
}

// ---------- kernel 3: GEMM2 F1p = w @ xt, F2 = e1 @ Ja ----------
// grid (9 p-tiles x 94 k-chunks of 64). Per block: stage A (w,e1 -> LDS [k][m],
// coalesced rows) and B (xt,Ja [k][p]); ONE barrier; inner loop pure LDS:
// 2x b128 (A) + 2x b64 (B) : 16 FMA per k. Atomic 94-way K-reduction.
#define G2_KC 64
#define G2_SA 68   // A row stride (floats): mult of 4 for b128, bank-ok reads
#define G2_SB 34   // B row stride (floats): mult of 2 for b64
__global__ __launch_bounds__(256, 3) void k_g2(const float* __restrict__ xt,
                                               const float* __restrict__ Ja,
                                               float* __restrict__ ws) {
  __shared__ __align__(16) float Asw[G2_KC * G2_SA];
  __shared__ __align__(16) float Ase[G2_KC * G2_SA];
  __shared__ __align__(16) float Bsv[G2_KC * G2_SB];
  __shared__ __align__(16) float Bsj[G2_KC * G2_SB];
  const int tid = threadIdx.x;
  const int p0 = blockIdx.x * 32;
  const int k0 = blockIdx.y * G2_KC;
  const float* w  = ws + OFF_W;
  const float* e1 = ws + OFF_E1;

  // stage A: 4 passes; thread reads float4 of w/e1 row m at k-quad, writes [k][m]
  {
    const int mq = tid >> 4;          // 0..15
    const int kq = (tid & 15) * 4;    // 0,4,..,60
    const int t = k0 + kq;
    const bool tv = (t < NT);         // t multiple of 4; NT%4==0 -> whole quad valid
#pragma unroll
    for (int pass = 0; pass < 4; pass++) {
      const int m = mq + 16 * pass;
      float4 w4 = make_float4(0.f, 0.f, 0.f, 0.f), e4 = w4;
      if (tv) {
        w4 = *(const float4*)(w  + (size_t)m * NT + t);
        e4 = *(const float4*)(e1 + (size_t)m * NT + t);
      }
#pragma unroll
      for (int j = 0; j < 4; j++) {
        Asw[(kq + j) * G2_SA + m] = f4c(w4, j);
        Ase[(kq + j) * G2_SA + m] = f4c(e4, j);
      }
    }
  }
  // stage B: 2 passes; thread reads float4 of xt/Ja row t at p-quad, writes [k][p]
  {
    const int pq = (tid & 7) * 4;     // 0,4,..,28
    const int kr = tid >> 3;          // 0..31
    const bool pv = (p0 + pq < NP);   // p-quads fully valid or fully invalid (276%4==0)
#pragma unroll
    for (int pass = 0; pass < 2; pass++) {
      const int k = kr + 32 * pass;
      const int t = k0 + k;
      float4 v4 = make_float4(0.f, 0.f, 0.f, 0.f), j4 = v4;
      if (pv && t < NT) {
        v4 = *(const float4*)(xt + (size_t)t * NP + p0 + pq);
        j4 = *(const float4*)(Ja + (size_t)t * NP + p0 + pq);
      }
#pragma unroll
      for (int j = 0; j < 4; j++) {
        Bsv[k * G2_SB + pq + j] = f4c(v4, j);
        Bsj[k * G2_SB + pq + j] = f4c(j4, j);
      }
    }
  }
  __syncthreads();

  const int c = tid & 15;   // p-pair: p = p0 + 2c + {0,1}
  const int r = tid >> 4;   // m-quad: m = 4r..4r+3
  float acc1[2][4] = {{0.f,0.f,0.f,0.f},{0.f,0.f,0.f,0.f}};
  float acc2[2][4] = {{0.f,0.f,0.f,0.f},{0.f,0.f,0.f,0.f}};

#pragma unroll
  for (int k = 0; k < G2_KC; k++) {
    const float4 aw = *(const float4*)(&Asw[k * G2_SA + r * 4]);
    const float4 ae = *(const float4*)(&Ase[k * G2_SA + r * 4]);
    const float2 bv = *(const float2*)(&Bsv[k * G2_SB + c * 2]);
    const float2 bj = *(const float2*)(&Bsj[k * G2_SB + c * 2]);
#pragma unroll
    for (int i = 0; i < 4; i++) {
      const float a1 = f4c(aw, i), a2 = f4c(ae, i);
      acc1[0][i] = fmaf(a1, bv.x, acc1[0][i]);
      acc1[1][i] = fmaf(a1, bv.y, acc1[1][i]);
      acc2[0][i] = fmaf(a2, bj.x, acc2[0][i]);
      acc2[1][i] = fmaf(a2, bj.y, acc2[1][i]);
    }
  }

  float* F1p = ws + OFF_F1P;
  float* F2  = ws + OFF_F2;
#pragma unroll
  for (int pp = 0; pp < 2; pp++) {
    const int p = p0 + c * 2 + pp;
    if (p < NP) {
#pragma unroll
      for (int i = 0; i < 4; i++) {
        atomicAdd(&F1p[(r * 4 + i) * NP + p], acc1[pp][i]);
        atomicAdd(&F2[(r * 4 + i) * NP + p],  acc2[pp][i]);
      }
    }
  }
}

// ---------- kernel 4: finalize ----------
__global__ __launch_bounds__(320) void k_final(const float* __restrict__ Rs,
                                               const float* __restrict__ ws,
                                               float* __restrict__ out) {
  const int m = blockIdx.x;
  const int tid = threadIdx.x;
  __shared__ float fx[NP];
  __shared__ float sR[NA * 3];
  if (tid < NA * 3) sR[tid] = Rs[m * NA * 3 + tid];
  const float sw = ws[OFF_SW + m];
  for (int p = tid; p < NP; p += 320) {
    float u = ws[OFF_XS + m * NP + p];
    float F1 = QC * (u * sw - ws[OFF_F1P + m * NP + p]);
    fx[p] = (F1 - ws[OFF_F2 + m * NP + p]) * u * u * u;
  }
  __syncthreads();
  if (tid == 0) out[m] = ws[OFF_ES + m] / QC;  // *STD + C, STD=1, C=0
  if (tid < NA * 3) {
    const int a = tid / 3, cc = tid % 3;
    const float ra = sR[a * 3 + cc];
    float acc = 0.f;
    for (int b = 0; b < NA; b++) {
      if (b == a) continue;
      const int i = a > b ? a : b, j = a > b ? b : a;
      const int p = i * (i - 1) / 2 + j;
      acc += (sR[b * 3 + cc] - ra) * fx[p];
    }
    out[MM + m * NA * 3 + tid] = acc;
  }
}

extern "C" void kernel_launch(void* const* d_in, const int* in_sizes, int n_in,
                              void* d_out, int out_size, void* d_ws, size_t ws_size,
                              hipStream_t stream) {
  const float* Rs = (const float*)d_in[0];
  const float* xt = (const float*)d_in[1];
  const float* Ja = (const float*)d_in[2];
  float* out = (float*)d_out;
  float* ws = (float*)d_ws;

  k_pre<<<MM + NT / 4, 256, 0, stream>>>(Rs, xt, Ja, ws);
  k_g1<<<NT / G1_TD, 256, 0, stream>>>(xt, Ja, ws);
  k_g2<<<dim3(9, (NT + G2_KC - 1) / G2_KC), 256, 0, stream>>>(xt, Ja, ws);
  k_final<<<MM, 320, 0, stream>>>(Rs, ws, out);
}

// Round 5
// 138.533 us; speedup vs baseline: 4.9571x; 4.9571x over previous
//
#include <hip/hip_runtime.h>
#include <math.h>

#define MM 64
#define NA 24
#define NP 276
#define NT 6000
#define QC 0.22360679774997896f
#define EXPC 0.01666666666666667f  // 5/(3*sig^2), sig=10

// ws layout (float offsets)
#define OFF_XS   0                 // 64*276
#define OFF_UU   17664             // 64
#define OFF_VV   17728             // 6000
#define OFF_C1   23728             // 6000
#define OFF_ES   29728             // 64     (zeroed)
#define OFF_SW   29792             // 64     (zeroed)
#define OFF_SH   29856             // 8 shadows * 2 arrays * [276][64] (zeroed)
#define OFF_WT   312480            // w  transposed [t][m] 6000*64
#define OFF_ET   696480            // e1 transposed [t][m] 6000*64
#define ZTOT     282752            // floats to zero at OFF_ES (es+sw+shadows)

__device__ __forceinline__ float f4c(const float4& v, int i) {
  return i == 0 ? v.x : i == 1 ? v.y : i == 2 ? v.z : v.w;
}

// ---------- kernel 1: prep (xs, uu) + stats (vv, c1) + zero accumulators ----------
__global__ __launch_bounds__(256) void k_pre(const float* __restrict__ Rs,
                                             const float* __restrict__ xt,
                                             const float* __restrict__ Ja,
                                             float* __restrict__ ws) {
  const int tid = threadIdx.x;
  for (int z = blockIdx.x * 256 + tid; z < ZTOT; z += gridDim.x * 256)
    ws[OFF_ES + z] = 0.f;

  if (blockIdx.x < MM) {
    const int m = blockIdx.x;
    __shared__ float sR[NA * 3];
    __shared__ float sAcc[4];
    if (tid < NA * 3) sR[tid] = Rs[m * NA * 3 + tid];
    __syncthreads();
    float acc = 0.f;
    for (int p = tid; p < NP; p += 256) {
      int i = (int)((1.0f + sqrtf(1.0f + 8.0f * (float)p)) * 0.5f);
      while (i * (i - 1) / 2 > p) i--;
      while ((i + 1) * i / 2 <= p) i++;
      int j = p - i * (i - 1) / 2;
      float dx = sR[i * 3 + 0] - sR[j * 3 + 0];
      float dy = sR[i * 3 + 1] - sR[j * 3 + 1];
      float dz = sR[i * 3 + 2] - sR[j * 3 + 2];
      float u = 1.0f / sqrtf(dx * dx + dy * dy + dz * dz);
      ws[OFF_XS + m * NP + p] = u;
      acc += u * u;
    }
    for (int off = 32; off; off >>= 1) acc += __shfl_down(acc, off);
    if ((tid & 63) == 0) sAcc[tid >> 6] = acc;
    __syncthreads();
    if (tid == 0) ws[OFF_UU + m] = sAcc[0] + sAcc[1] + sAcc[2] + sAcc[3];
  } else {
    const int t = (blockIdx.x - MM) * 4 + (tid >> 6);
    const int lane = tid & 63;
    if (t < NT) {
      const float* vrow = xt + (size_t)t * NP;
      const float* jrow = Ja + (size_t)t * NP;
      float a = 0.f, b = 0.f;
      for (int p = lane; p < NP; p += 64) {
        float v = vrow[p], j = jrow[p];
        a += v * v;
        b += v * j;
      }
      for (int off = 32; off; off >>= 1) {
        a += __shfl_down(a, off);
        b += __shfl_down(b, off);
      }
      if (lane == 0) { ws[OFF_VV + t] = a; ws[OFF_C1 + t] = b; }
    }
  }
}

// ---------- kernel 2: fused GEMM1 + elementwise, writes wT/e1T (t-major) ----------
// grid (375 t-tiles, 4 m-quarters); block 128 = tile 16m x 16t; thread = 1m x 2t.
// B (xt,Ja interleaved) staged in LDS once; A (xs) streamed from L1/L2
// (1 float4 per 4k, broadcast across the 8 c-lanes). One barrier total.
#define G1_BS 278  // float2 stride per t-row (276 + 2 pad, even for 16B align)
__global__ __launch_bounds__(128) void k_g1(const float* __restrict__ xt,
                                            const float* __restrict__ Ja,
                                            float* __restrict__ ws) {
  __shared__ __align__(16) float2 Bs[16][G1_BS];
  const int tid = threadIdx.x;
  const int t0 = blockIdx.x * 16;
  const int my = blockIdx.y * 16;
  // stage B: 16 rows x 69 float4-quads per matrix
  for (int idx = tid; idx < 16 * 69; idx += 128) {
    const int row = idx / 69;
    const int k = (idx - row * 69) * 4;
    const float4 v = *(const float4*)(xt + (size_t)(t0 + row) * NP + k);
    const float4 j = *(const float4*)(Ja + (size_t)(t0 + row) * NP + k);
    *(float4*)&Bs[row][k]     = make_float4(v.x, j.x, v.y, j.y);
    *(float4*)&Bs[row][k + 2] = make_float4(v.z, j.z, v.w, j.w);
  }
  const int r = tid >> 3;   // m-local 0..15
  const int c = tid & 7;    // t-pair
  const int m = my + r;
  const float uum = ws[OFF_UU + m];
  const float2 vv2 = *(const float2*)(ws + OFF_VV + t0 + 2 * c);
  const float2 c12 = *(const float2*)(ws + OFF_C1 + t0 + 2 * c);
  const float* arow = ws + OFF_XS + m * NP;
  __syncthreads();

  float accv0 = 0.f, accj0 = 0.f, accv1 = 0.f, accj1 = 0.f;
#pragma unroll 3
  for (int k = 0; k < NP; k += 4) {
    const float4 a = *(const float4*)(arow + k);
    const float4 p00 = *(const float4*)&Bs[2 * c][k];      // (v,j,v,j) k,k+1
    const float4 p01 = *(const float4*)&Bs[2 * c][k + 2];
    const float4 p10 = *(const float4*)&Bs[2 * c + 1][k];
    const float4 p11 = *(const float4*)&Bs[2 * c + 1][k + 2];
    accv0 = fmaf(a.x, p00.x, accv0); accj0 = fmaf(a.x, p00.y, accj0);
    accv0 = fmaf(a.y, p00.z, accv0); accj0 = fmaf(a.y, p00.w, accj0);
    accv0 = fmaf(a.z, p01.x, accv0); accj0 = fmaf(a.z, p01.y, accj0);
    accv0 = fmaf(a.w, p01.z, accv0); accj0 = fmaf(a.w, p01.w, accj0);
    accv1 = fmaf(a.x, p10.x, accv1); accj1 = fmaf(a.x, p10.y, accj1);
    accv1 = fmaf(a.y, p10.z, accv1); accj1 = fmaf(a.y, p10.w, accj1);
    accv1 = fmaf(a.z, p11.x, accv1); accj1 = fmaf(a.z, p11.y, accj1);
    accv1 = fmaf(a.w, p11.z, accv1); accj1 = fmaf(a.w, p11.w, accj1);
  }

  // elementwise epilogue for t = t0+2c, t0+2c+1
  float es_p = 0.f, sw_p = 0.f;
#pragma unroll
  for (int tt = 0; tt < 2; tt++) {
    const float g1v = tt ? accv1 : accv0;
    const float g2v = tt ? accj1 : accj0;
    const float vvt = tt ? vv2.y : vv2.x;
    const float c1t = tt ? c12.y : c12.x;
    float d2 = fmaxf(uum - 2.f * g1v + vvt, 0.f);
    float xd = QC * sqrtf(d2);
    float dv = QC * (g2v - c1t);
    float ex = EXPC * __expf(-xd);
    float e1v = ex * (1.f + xd);
    float w_ = ex * dv;
    const int t = t0 + 2 * c + tt;
    ws[OFF_WT + (size_t)t * 64 + m] = w_;
    ws[OFF_ET + (size_t)t * 64 + m] = e1v;
    es_p += e1v * dv;
    sw_p += w_;
  }
  // reduce across the 8 c-lanes of this m, then one atomic per (block,m)
#pragma unroll
  for (int off = 4; off; off >>= 1) {
    es_p += __shfl_down(es_p, off);
    sw_p += __shfl_down(sw_p, off);
  }
  if (c == 0) {
    atomicAdd(ws + OFF_ES + m, es_p);
    atomicAdd(ws + OFF_SW + m, sw_p);
  }
}

// ---------- kernel 3: GEMM2 partials: shadow[s][0] += w@xt, shadow[s][1] += e1@Ja ----------
// grid (18 p-tiles x 48 k-chunks of 125); block 256: lane = m (0..63), wave = p-group.
// Per k: 2 coalesced b32 A-loads (wT/e1T) + 2 broadcast b128 LDS B-reads + 8 FMA.
// Epilogue: lane-coalesced atomics into shadow (kc&7), [p][m] layout.
#define G2_KC 125
__global__ __launch_bounds__(256) void k_g2(const float* __restrict__ xt,
                                            const float* __restrict__ Ja,
                                            float* __restrict__ ws) {
  __shared__ __align__(16) float Bsv[G2_KC][16];
  __shared__ __align__(16) float Bsj[G2_KC][16];
  const int tid = threadIdx.x;
  const int p0 = blockIdx.x * 16;
  const int k0 = blockIdx.y * G2_KC;
  const int validp = (NP - p0 < 16) ? (NP - p0) : 16;

  // stage B: 125 rows x 2 mats x 4 quads
  for (int idx = tid; idx < G2_KC * 8; idx += 256) {
    const int q = idx & 3;
    const int mat = (idx >> 2) & 1;
    const int row = idx >> 3;
    float4 val = make_float4(0.f, 0.f, 0.f, 0.f);
    if (q * 4 < validp)
      val = *(const float4*)((mat ? Ja : xt) + (size_t)(k0 + row) * NP + p0 + q * 4);
    *(float4*)&(mat ? Bsj : Bsv)[row][q * 4] = val;
  }
  __syncthreads();

  const int m = tid & 63;
  const int pg = tid >> 6;  // 0..3
  const float* wtp = ws + OFF_WT + (size_t)k0 * 64 + m;
  const float* etp = ws + OFF_ET + (size_t)k0 * 64 + m;
  float acc1[4] = {0.f, 0.f, 0.f, 0.f};
  float acc2[4] = {0.f, 0.f, 0.f, 0.f};

#pragma unroll 5
  for (int k = 0; k < G2_KC; k++) {
    const float aw = wtp[k * 64];
    const float ae = etp[k * 64];
    const float4 bv = *(const float4*)&Bsv[k][pg * 4];
    const float4 bj = *(const float4*)&Bsj[k][pg * 4];
    acc1[0] = fmaf(aw, bv.x, acc1[0]); acc2[0] = fmaf(ae, bj.x, acc2[0]);
    acc1[1] = fmaf(aw, bv.y, acc1[1]); acc2[1] = fmaf(ae, bj.y, acc2[1]);
    acc1[2] = fmaf(aw, bv.z, acc1[2]); acc2[2] = fmaf(ae, bj.z, acc2[2]);
    acc1[3] = fmaf(aw, bv.w, acc1[3]); acc2[3] = fmaf(ae, bj.w, acc2[3]);
  }

  const int sh = blockIdx.y & 7;
  float* base1 = ws + OFF_SH + (size_t)(sh * 2 + 0) * NP * 64;
  float* base2 = ws + OFF_SH + (size_t)(sh * 2 + 1) * NP * 64;
#pragma unroll
  for (int j = 0; j < 4; j++) {
    const int p = p0 + pg * 4 + j;
    if (p < NP && pg * 4 + j < validp) {
      atomicAdd(base1 + (size_t)p * 64 + m, acc1[j]);
      atomicAdd(base2 + (size_t)p * 64 + m, acc2[j]);
    }
  }
}

// ---------- kernel 4: finalize (reduce shadows, force gather, Es) ----------
__global__ __launch_bounds__(320) void k_final(const float* __restrict__ Rs,
                                               const float* __restrict__ ws,
                                               float* __restrict__ out) {
  const int m = blockIdx.x;
  const int tid = threadIdx.x;
  __shared__ float fx[NP];
  __shared__ float sR[NA * 3];
  if (tid < NA * 3) sR[tid] = Rs[m * NA * 3 + tid];
  const float sw = ws[OFF_SW + m];
  for (int p = tid; p < NP; p += 320) {
    float f1p = 0.f, f2 = 0.f;
#pragma unroll
    for (int s = 0; s < 8; s++) {
      f1p += ws[OFF_SH + ((size_t)(s * 2 + 0) * NP + p) * 64 + m];
      f2  += ws[OFF_SH + ((size_t)(s * 2 + 1) * NP + p) * 64 + m];
    }
    const float u = ws[OFF_XS + m * NP + p];
    const float F1 = QC * (u * sw - f1p);
    fx[p] = (F1 - f2) * u * u * u;
  }
  __syncthreads();
  if (tid == 0) out[m] = ws[OFF_ES + m] / QC;  // *STD + C, STD=1, C=0
  if (tid < NA * 3) {
    const int a = tid / 3, cc = tid % 3;
    const float ra = sR[a * 3 + cc];
    float acc = 0.f;
    for (int b = 0; b < NA; b++) {
      if (b == a) continue;
      const int i = a > b ? a : b, j = a > b ? b : a;
      const int p = i * (i - 1) / 2 + j;
      acc += (sR[b * 3 + cc] - ra) * fx[p];
    }
    out[MM + m * NA * 3 + tid] = acc;
  }
}

extern "C" void kernel_launch(void* const* d_in, const int* in_sizes, int n_in,
                              void* d_out, int out_size, void* d_ws, size_t ws_size,
                              hipStream_t stream) {
  const float* Rs = (const float*)d_in[0];
  const float* xt = (const float*)d_in[1];
  const float* Ja = (const float*)d_in[2];
  float* out = (float*)d_out;
  float* ws = (float*)d_ws;

  k_pre<<<MM + NT / 4, 256, 0, stream>>>(Rs, xt, Ja, ws);
  k_g1<<<dim3(NT / 16, 4), 128, 0, stream>>>(xt, Ja, ws);
  k_g2<<<dim3(18, NT / G2_KC), 256, 0, stream>>>(xt, Ja, ws);
  k_final<<<MM, 320, 0, stream>>>(Rs, ws, out);
}